// Round 2
// baseline (3592.782 us; speedup 1.0000x reference)
//
#include <hip/hip_runtime.h>
#include <hip/hip_bf16.h>
#include <math.h>

#define NN 50000
#define EE 200000
#define DD 256
#define HH 8
#define DKK 32

constexpr float RSQRT_DK = 0.17677669529663687f;  // 1/sqrt(32)

__device__ __forceinline__ float bf_lo(unsigned u) { return __uint_as_float(u << 16); }
__device__ __forceinline__ float bf_hi(unsigned u) { return __uint_as_float(u & 0xffff0000u); }
__device__ __forceinline__ unsigned short f2bf(float f) {
    unsigned u = __float_as_uint(f);
    return (unsigned short)((u + 0x7fffu + ((u >> 16) & 1u)) >> 16);  // RNE
}

// ---------------------------------------------------------------------------
// SGEMM: C[nrows,256] = X[nrows,256] @ W[256,256] + bias
// Cbf != null -> write bf16 instead of fp32.
// xres != null -> C = C*sigmoid(skip) + xres*(1-sigmoid(skip))
// ---------------------------------------------------------------------------
__global__ void sgemm_kernel(const float* __restrict__ X, const float* __restrict__ W,
                             const float* __restrict__ bias, float* __restrict__ C,
                             unsigned short* __restrict__ Cbf,
                             int nrows, const float* __restrict__ xres,
                             const float* __restrict__ skip) {
    __shared__ __align__(16) float As[16][64];  // [k][m]
    __shared__ __align__(16) float Bs[16][64];  // [k][n]
    const int t = threadIdx.x;
    const int row0 = blockIdx.x * 64, col0 = blockIdx.y * 64;
    const int tr = t >> 4, tc = t & 15;
    float acc[4][4] = {};

    const int ra  = row0 + (t >> 2);
    const int kk4 = (t & 3) << 2;

    for (int k0 = 0; k0 < 256; k0 += 16) {
        float4 a4 = make_float4(0.f, 0.f, 0.f, 0.f);
        if (ra < nrows) a4 = *(const float4*)&X[(size_t)ra * 256 + k0 + kk4];
        As[kk4 + 0][t >> 2] = a4.x;
        As[kk4 + 1][t >> 2] = a4.y;
        As[kk4 + 2][t >> 2] = a4.z;
        As[kk4 + 3][t >> 2] = a4.w;
        *(float4*)&Bs[t >> 4][(t & 15) << 2] =
            *(const float4*)&W[(size_t)(k0 + (t >> 4)) * 256 + col0 + ((t & 15) << 2)];
        __syncthreads();
        #pragma unroll
        for (int kk = 0; kk < 16; ++kk) {
            float4 av = *(const float4*)&As[kk][tr << 2];
            float4 bv = *(const float4*)&Bs[kk][tc << 2];
            acc[0][0] += av.x * bv.x; acc[0][1] += av.x * bv.y;
            acc[0][2] += av.x * bv.z; acc[0][3] += av.x * bv.w;
            acc[1][0] += av.y * bv.x; acc[1][1] += av.y * bv.y;
            acc[1][2] += av.y * bv.z; acc[1][3] += av.y * bv.w;
            acc[2][0] += av.z * bv.x; acc[2][1] += av.z * bv.y;
            acc[2][2] += av.z * bv.z; acc[2][3] += av.z * bv.w;
            acc[3][0] += av.w * bv.x; acc[3][1] += av.w * bv.y;
            acc[3][2] += av.w * bv.z; acc[3][3] += av.w * bv.w;
        }
        __syncthreads();
    }

    float alpha = 1.f, beta = 0.f;
    if (skip) { alpha = 1.f / (1.f + __expf(-skip[0])); beta = 1.f - alpha; }
    const int col = col0 + (tc << 2);
    #pragma unroll
    for (int i = 0; i < 4; ++i) {
        int row = row0 + (tr << 2) + i;
        if (row >= nrows) break;
        float4 o;
        o.x = acc[i][0] + bias[col + 0];
        o.y = acc[i][1] + bias[col + 1];
        o.z = acc[i][2] + bias[col + 2];
        o.w = acc[i][3] + bias[col + 3];
        if (xres) {
            float4 xr = *(const float4*)&xres[(size_t)row * 256 + col];
            o.x = o.x * alpha + xr.x * beta;
            o.y = o.y * alpha + xr.y * beta;
            o.z = o.z * alpha + xr.z * beta;
            o.w = o.w * alpha + xr.w * beta;
        }
        if (Cbf) {
            ushort4 ob;
            ob.x = f2bf(o.x); ob.y = f2bf(o.y); ob.z = f2bf(o.z); ob.w = f2bf(o.w);
            *(ushort4*)&Cbf[(size_t)row * 256 + col] = ob;
        } else {
            *(float4*)&C[(size_t)row * 256 + col] = o;
        }
    }
}

// ---------------------------------------------------------------------------
// Per-node head transform: out[n,h,f] = sum_d in[n,h,d] * A[h,d,f], bf16 out.
// Wave-per-node: lane = h*8+j computes outputs f = 4j..4j+3.
// A staged in LDS, head stride 1028 floats (16B-aligned, de-phased banks).
// ---------------------------------------------------------------------------
#define ASTRIDE 1028
__global__ void transform_kernel(const float* __restrict__ in, const float* __restrict__ A_g,
                                 unsigned short* __restrict__ out_bf) {
    __shared__ __align__(16) float A[HH * ASTRIDE];
    for (int i = threadIdx.x; i < HH * DKK * DKK; i += 256) {
        int h = i >> 10;
        A[h * ASTRIDE + (i & 1023)] = A_g[i];
    }
    __syncthreads();
    const int wave = threadIdx.x >> 6, lane = threadIdx.x & 63;
    const int h = lane >> 3, j = lane & 7;
    const int n = blockIdx.x * 4 + wave;  // grid = NN/4 exact

    float rbuf[32];
    const float* rowp = &in[(size_t)n * 256 + h * 32];
    #pragma unroll
    for (int c = 0; c < 8; ++c) *(float4*)&rbuf[c * 4] = *(const float4*)&rowp[c * 4];

    float4 acc = make_float4(0.f, 0.f, 0.f, 0.f);
    const float* Ah = &A[h * ASTRIDE + j * 4];
    #pragma unroll
    for (int d = 0; d < 32; ++d) {
        float rv = rbuf[d];
        float4 av = *(const float4*)&Ah[d * 32];
        acc.x += rv * av.x; acc.y += rv * av.y;
        acc.z += rv * av.z; acc.w += rv * av.w;
    }
    ushort4 ob;
    ob.x = f2bf(acc.x); ob.y = f2bf(acc.y); ob.z = f2bf(acc.z); ob.w = f2bf(acc.w);
    *(ushort4*)&out_bf[(size_t)n * 256 + h * 32 + j * 4] = ob;
}

// ---------------------------------------------------------------------------
// Pass A: 32 lanes per edge (lane = h*4+quad, 8 dims each, uint4 bf16 loads).
// att[h] = dot(q[dst,h], kt[src,h]) * pri[h]/sqrt(dk); store exp, atomic den.
// (Max-pass skipped: att ~ N(0,1); softmax shift-invariant, exp can't overflow.)
// ---------------------------------------------------------------------------
__global__ void edge_att_kernel(const unsigned short* __restrict__ q,
                                const unsigned short* __restrict__ kt,
                                const int* __restrict__ src, const int* __restrict__ dst,
                                const float* __restrict__ pri,
                                float* __restrict__ expatt, float* __restrict__ den) {
    const int half = threadIdx.x >> 5;            // 8 edge-slots per block
    const int ll = threadIdx.x & 31;
    const int h = ll >> 2, quad = ll & 3;
    const int e = blockIdx.x * 8 + half;
    const int s = src[e], d_ = dst[e];
    const size_t off = (size_t)(h * 32 + quad * 8);

    uint4 a = *(const uint4*)&q[(size_t)d_ * 256 + off];
    uint4 b = *(const uint4*)&kt[(size_t)s * 256 + off];
    float p = bf_lo(a.x) * bf_lo(b.x) + bf_hi(a.x) * bf_hi(b.x)
            + bf_lo(a.y) * bf_lo(b.y) + bf_hi(a.y) * bf_hi(b.y)
            + bf_lo(a.z) * bf_lo(b.z) + bf_hi(a.z) * bf_hi(b.z)
            + bf_lo(a.w) * bf_lo(b.w) + bf_hi(a.w) * bf_hi(b.w);
    p += __shfl_xor(p, 1);
    p += __shfl_xor(p, 2);
    if (quad == 0) {
        float av = __expf(p * pri[h] * RSQRT_DK);
        expatt[(size_t)e * HH + h] = av;
        atomicAdd(&den[(size_t)d_ * HH + h], av);
    }
}

// ---------------------------------------------------------------------------
// Pass B: t[dst] += 0.5 * (expatt/den[dst]) * vt[src]   (mean over R=2 fused)
// ---------------------------------------------------------------------------
__global__ void edge_agg_kernel(const unsigned short* __restrict__ vt,
                                const int* __restrict__ src, const int* __restrict__ dst,
                                const float* __restrict__ expatt,
                                const float* __restrict__ den, float* __restrict__ t) {
    const int half = threadIdx.x >> 5;
    const int ll = threadIdx.x & 31;
    const int h = ll >> 2, quad = ll & 3;
    const int e = blockIdx.x * 8 + half;
    const int s = src[e], d_ = dst[e];
    const float w = 0.5f * expatt[(size_t)e * HH + h] / den[(size_t)d_ * HH + h];
    const size_t off = (size_t)(h * 32 + quad * 8);

    uint4 b = *(const uint4*)&vt[(size_t)s * 256 + off];
    float* tp = &t[(size_t)d_ * 256 + off];
    atomicAdd(tp + 0, w * bf_lo(b.x)); atomicAdd(tp + 1, w * bf_hi(b.x));
    atomicAdd(tp + 2, w * bf_lo(b.y)); atomicAdd(tp + 3, w * bf_hi(b.y));
    atomicAdd(tp + 4, w * bf_lo(b.z)); atomicAdd(tp + 5, w * bf_hi(b.z));
    atomicAdd(tp + 6, w * bf_lo(b.w)); atomicAdd(tp + 7, w * bf_hi(b.w));
}

// ---------------------------------------------------------------------------
extern "C" void kernel_launch(void* const* d_in, const int* in_sizes, int n_in,
                              void* d_out, int out_size, void* d_ws, size_t ws_size,
                              hipStream_t stream) {
    const float* x       = (const float*)d_in[0];
    const int*   src     = (const int*)d_in[1];
    const int*   dst     = (const int*)d_in[2];
    const float* Wk      = (const float*)d_in[3];
    const float* bk      = (const float*)d_in[4];
    const float* Wq      = (const float*)d_in[5];
    const float* bq      = (const float*)d_in[6];
    const float* Wv      = (const float*)d_in[7];
    const float* bv      = (const float*)d_in[8];
    const float* Wa      = (const float*)d_in[9];
    const float* ba      = (const float*)d_in[10];
    const float* rel_pri = (const float*)d_in[11];
    const float* rel_att = (const float*)d_in[12];
    const float* rel_msg = (const float*)d_in[13];
    const float* skip    = (const float*)d_in[14];
    float* out = (float*)d_out;
    char* ws = (char*)d_ws;

    const size_t ND = (size_t)NN * DD;
    size_t off = 0;
    unsigned short* q_bf  = (unsigned short*)(ws + off); off += ND * 2;          // 25.6MB
    float*          k     = (float*)(ws + off);          off += ND * 4;          // 51.2MB
    float*          v     = (float*)(ws + off);          off += ND * 4;          // 51.2MB
    unsigned short* tb_bf = (unsigned short*)(ws + off); off += ND * 2;          // 25.6MB
    float*          tt    = (float*)(ws + off);          off += ND * 4;          // 51.2MB
    float*          expatt= (float*)(ws + off);          off += (size_t)EE * HH * 4;  // 6.4MB
    float*          den   = (float*)(ws + off);          off += (size_t)NN * HH * 4;  // 1.6MB
    if (ws_size < off) return;  // visible failure if workspace too small

    dim3 gg((NN + 63) / 64, DD / 64);
    sgemm_kernel<<<gg, 256, 0, stream>>>(x, Wq, bq, nullptr, q_bf, NN, nullptr, nullptr);
    sgemm_kernel<<<gg, 256, 0, stream>>>(x, Wk, bk, k, nullptr, NN, nullptr, nullptr);
    sgemm_kernel<<<gg, 256, 0, stream>>>(x, Wv, bv, v, nullptr, NN, nullptr, nullptr);
    hipMemsetAsync(tt, 0, ND * sizeof(float), stream);

    const int tgrid = NN / 4;       // 12500, exact
    const int egrid = EE / 8;       // 25000, exact
    for (int r = 0; r < 2; ++r) {
        transform_kernel<<<tgrid, 256, 0, stream>>>(k, rel_att + (size_t)r * HH * DKK * DKK, tb_bf);
        hipMemsetAsync(den, 0, (size_t)NN * HH * sizeof(float), stream);
        edge_att_kernel<<<egrid, 256, 0, stream>>>(q_bf, tb_bf, src + (size_t)r * EE,
                                                   dst + (size_t)r * EE,
                                                   rel_pri + (size_t)r * HH, expatt, den);
        transform_kernel<<<tgrid, 256, 0, stream>>>(v, rel_msg + (size_t)r * HH * DKK * DKK, tb_bf);
        edge_agg_kernel<<<egrid, 256, 0, stream>>>(tb_bf, src + (size_t)r * EE,
                                                   dst + (size_t)r * EE, expatt, den, tt);
    }
    sgemm_kernel<<<gg, 256, 0, stream>>>(tt, Wa, ba, out, nullptr, NN, x, skip);
}

// Round 3
// 1259.231 us; speedup vs baseline: 2.8532x; 2.8532x over previous
//
#include <hip/hip_runtime.h>
#include <hip/hip_bf16.h>
#include <math.h>

#define NN 50000
#define EE 200000
#define DD 256
#define HH 8
#define DKK 32
#define NSEG (2 * NN)

constexpr float RSQRT_DK = 0.17677669529663687f;  // 1/sqrt(32)

__device__ __forceinline__ float bf_lo(unsigned u) { return __uint_as_float(u << 16); }
__device__ __forceinline__ float bf_hi(unsigned u) { return __uint_as_float(u & 0xffff0000u); }
__device__ __forceinline__ unsigned short f2bf(float f) {
    unsigned u = __float_as_uint(f);
    return (unsigned short)((u + 0x7fffu + ((u >> 16) & 1u)) >> 16);  // RNE
}

// ---------------------------------------------------------------------------
// SGEMM: C[nrows,256] = X[nrows,256] @ W[256,256] + bias (fp32 or bf16 out;
// optional skip-gate epilogue). 64x64 tile, BK=16, 4x4 micro-tile.
// ---------------------------------------------------------------------------
__global__ void sgemm_kernel(const float* __restrict__ X, const float* __restrict__ W,
                             const float* __restrict__ bias, float* __restrict__ C,
                             unsigned short* __restrict__ Cbf,
                             int nrows, const float* __restrict__ xres,
                             const float* __restrict__ skip) {
    __shared__ __align__(16) float As[16][64];
    __shared__ __align__(16) float Bs[16][64];
    const int t = threadIdx.x;
    const int row0 = blockIdx.x * 64, col0 = blockIdx.y * 64;
    const int tr = t >> 4, tc = t & 15;
    float acc[4][4] = {};

    const int ra  = row0 + (t >> 2);
    const int kk4 = (t & 3) << 2;

    for (int k0 = 0; k0 < 256; k0 += 16) {
        float4 a4 = make_float4(0.f, 0.f, 0.f, 0.f);
        if (ra < nrows) a4 = *(const float4*)&X[(size_t)ra * 256 + k0 + kk4];
        As[kk4 + 0][t >> 2] = a4.x;
        As[kk4 + 1][t >> 2] = a4.y;
        As[kk4 + 2][t >> 2] = a4.z;
        As[kk4 + 3][t >> 2] = a4.w;
        *(float4*)&Bs[t >> 4][(t & 15) << 2] =
            *(const float4*)&W[(size_t)(k0 + (t >> 4)) * 256 + col0 + ((t & 15) << 2)];
        __syncthreads();
        #pragma unroll
        for (int kk = 0; kk < 16; ++kk) {
            float4 av = *(const float4*)&As[kk][tr << 2];
            float4 bv = *(const float4*)&Bs[kk][tc << 2];
            acc[0][0] += av.x * bv.x; acc[0][1] += av.x * bv.y;
            acc[0][2] += av.x * bv.z; acc[0][3] += av.x * bv.w;
            acc[1][0] += av.y * bv.x; acc[1][1] += av.y * bv.y;
            acc[1][2] += av.y * bv.z; acc[1][3] += av.y * bv.w;
            acc[2][0] += av.z * bv.x; acc[2][1] += av.z * bv.y;
            acc[2][2] += av.z * bv.z; acc[2][3] += av.z * bv.w;
            acc[3][0] += av.w * bv.x; acc[3][1] += av.w * bv.y;
            acc[3][2] += av.w * bv.z; acc[3][3] += av.w * bv.w;
        }
        __syncthreads();
    }

    float alpha = 1.f, beta = 0.f;
    if (skip) { alpha = 1.f / (1.f + __expf(-skip[0])); beta = 1.f - alpha; }
    const int col = col0 + (tc << 2);
    #pragma unroll
    for (int i = 0; i < 4; ++i) {
        int row = row0 + (tr << 2) + i;
        if (row >= nrows) break;
        float4 o;
        o.x = acc[i][0] + bias[col + 0];
        o.y = acc[i][1] + bias[col + 1];
        o.z = acc[i][2] + bias[col + 2];
        o.w = acc[i][3] + bias[col + 3];
        if (xres) {
            float4 xr = *(const float4*)&xres[(size_t)row * 256 + col];
            o.x = o.x * alpha + xr.x * beta;
            o.y = o.y * alpha + xr.y * beta;
            o.z = o.z * alpha + xr.z * beta;
            o.w = o.w * alpha + xr.w * beta;
        }
        if (Cbf) {
            ushort4 ob;
            ob.x = f2bf(o.x); ob.y = f2bf(o.y); ob.z = f2bf(o.z); ob.w = f2bf(o.w);
            *(ushort4*)&Cbf[(size_t)row * 256 + col] = ob;
        } else {
            *(float4*)&C[(size_t)row * 256 + col] = o;
        }
    }
}

// ---------------------------------------------------------------------------
// Per-node head transform: out[n,h,f] = sum_d in[n,h,d] * A[h,d,f], bf16 out.
// ---------------------------------------------------------------------------
#define ASTRIDE 1028
__global__ void transform_kernel(const float* __restrict__ in, const float* __restrict__ A_g,
                                 unsigned short* __restrict__ out_bf) {
    __shared__ __align__(16) float A[HH * ASTRIDE];
    for (int i = threadIdx.x; i < HH * DKK * DKK; i += 256) {
        int h = i >> 10;
        A[h * ASTRIDE + (i & 1023)] = A_g[i];
    }
    __syncthreads();
    const int wave = threadIdx.x >> 6, lane = threadIdx.x & 63;
    const int h = lane >> 3, j = lane & 7;
    const int n = blockIdx.x * 4 + wave;  // grid = NN/4 exact

    float rbuf[32];
    const float* rowp = &in[(size_t)n * 256 + h * 32];
    #pragma unroll
    for (int c = 0; c < 8; ++c) *(float4*)&rbuf[c * 4] = *(const float4*)&rowp[c * 4];

    float4 acc = make_float4(0.f, 0.f, 0.f, 0.f);
    const float* Ah = &A[h * ASTRIDE + j * 4];
    #pragma unroll
    for (int d = 0; d < 32; ++d) {
        float rv = rbuf[d];
        float4 av = *(const float4*)&Ah[d * 32];
        acc.x += rv * av.x; acc.y += rv * av.y;
        acc.z += rv * av.z; acc.w += rv * av.w;
    }
    ushort4 ob;
    ob.x = f2bf(acc.x); ob.y = f2bf(acc.y); ob.z = f2bf(acc.z); ob.w = f2bf(acc.w);
    *(ushort4*)&out_bf[(size_t)n * 256 + h * 32 + j * 4] = ob;
}

// ---------------------------------------------------------------------------
// CSR build: count -> scan -> scatter. Segment = r*NN + dst.
// ---------------------------------------------------------------------------
__global__ void count_kernel(const int* __restrict__ dst, int* __restrict__ cnt) {
    int e = blockIdx.x * 256 + threadIdx.x;
    if (e < 2 * EE) atomicAdd(&cnt[(e / EE) * NN + dst[e]], 1);
}

__global__ __launch_bounds__(1024) void scan_kernel(const int* __restrict__ cnt,
                                                    int* __restrict__ rowptr) {
    const int n = NSEG;                 // 100000
    const int C = (n + 1023) / 1024;    // 98
    const int t = threadIdx.x;
    const int base = t * C;
    int run = 0;
    for (int i = 0; i < C; ++i) {
        int idx = base + i;
        int c = (idx < n) ? cnt[idx] : 0;
        if (idx < n) rowptr[idx] = run;  // local exclusive
        run += c;
    }
    __shared__ int sh[1024];
    sh[t] = run;
    __syncthreads();
    for (int ofs = 1; ofs < 1024; ofs <<= 1) {   // Hillis-Steele inclusive
        int v = (t >= ofs) ? sh[t - ofs] : 0;
        __syncthreads();
        sh[t] += v;
        __syncthreads();
    }
    int excl = sh[t] - run;
    for (int i = 0; i < C; ++i) {
        int idx = base + i;
        if (idx < n) rowptr[idx] += excl;
    }
    if (t == 1023) rowptr[n] = sh[1023];
}

__global__ void scatter_kernel(const int* __restrict__ src, const int* __restrict__ dst,
                               int* __restrict__ cursor, int* __restrict__ csr_src,
                               int* __restrict__ csr_eid) {
    int e = blockIdx.x * 256 + threadIdx.x;
    if (e >= 2 * EE) return;
    int r = e / EE;
    int seg = r * NN + dst[e];
    int pos = atomicAdd(&cursor[seg], 1);
    csr_src[pos] = src[e];
    csr_eid[pos] = e - r * EE;  // local edge id (expatt is per-relation)
}

// ---------------------------------------------------------------------------
// Pass A: expatt[e,h] = exp(dot(q[dst,h], kt[src,h]) * pri[h]/sqrt(dk)).
// 32 lanes/edge; max-pass skipped (att ~ N(0,1), softmax shift-invariant).
// ---------------------------------------------------------------------------
__global__ void edge_att_kernel(const unsigned short* __restrict__ q,
                                const unsigned short* __restrict__ kt,
                                const int* __restrict__ src, const int* __restrict__ dst,
                                const float* __restrict__ pri,
                                float* __restrict__ expatt) {
    const int half = threadIdx.x >> 5;
    const int ll = threadIdx.x & 31;
    const int h = ll >> 2, quad = ll & 3;
    const int e = blockIdx.x * 8 + half;
    const int s = src[e], d_ = dst[e];
    const size_t off = (size_t)(h * 32 + quad * 8);

    uint4 a = *(const uint4*)&q[(size_t)d_ * 256 + off];
    uint4 b = *(const uint4*)&kt[(size_t)s * 256 + off];
    float p = bf_lo(a.x) * bf_lo(b.x) + bf_hi(a.x) * bf_hi(b.x)
            + bf_lo(a.y) * bf_lo(b.y) + bf_hi(a.y) * bf_hi(b.y)
            + bf_lo(a.z) * bf_lo(b.z) + bf_hi(a.z) * bf_hi(b.z)
            + bf_lo(a.w) * bf_lo(b.w) + bf_hi(a.w) * bf_hi(b.w);
    p += __shfl_xor(p, 1);
    p += __shfl_xor(p, 2);
    if (quad == 0) {
        expatt[(size_t)e * HH + h] = __expf(p * pri[h] * RSQRT_DK);
    }
}

// ---------------------------------------------------------------------------
// Pass B (CSR gather, NO atomics): one wave per node. Lane owns 4 consecutive
// floats (head h = lane>>3). Accumulate num = sum e_i * vt[src_i], den = sum e_i
// over the node's incoming edges; tt[n] (+)= 0.5 * num/den. r=0 writes, r=1 adds.
// ---------------------------------------------------------------------------
__global__ void node_agg_kernel(const unsigned short* __restrict__ vt,
                                const int* __restrict__ csr_src,
                                const int* __restrict__ csr_eid,
                                const int* __restrict__ rowptr,
                                const float* __restrict__ expatt,
                                float* __restrict__ tt, int r) {
    const int wave = threadIdx.x >> 6, lane = threadIdx.x & 63;
    const int n = blockIdx.x * 4 + wave;  // grid = NN/4 exact
    const int h = lane >> 3;
    const int off = lane * 4;
    const int seg = r * NN + n;
    const int j0 = rowptr[seg], j1 = rowptr[seg + 1];

    float4 acc = make_float4(0.f, 0.f, 0.f, 0.f);
    float den = 0.f;
    for (int j = j0; j < j1; ++j) {
        const int s = csr_src[j];
        const int e = csr_eid[j];
        const float a = expatt[(size_t)e * HH + h];
        den += a;
        uint2 b = *(const uint2*)&vt[(size_t)s * 256 + off];
        acc.x += a * bf_lo(b.x);
        acc.y += a * bf_hi(b.x);
        acc.z += a * bf_lo(b.y);
        acc.w += a * bf_hi(b.y);
    }
    const float w = (den > 0.f) ? 0.5f / den : 0.f;
    float4 o = make_float4(acc.x * w, acc.y * w, acc.z * w, acc.w * w);
    float* tp = &tt[(size_t)n * 256 + off];
    if (r == 0) {
        *(float4*)tp = o;
    } else {
        float4 p = *(const float4*)tp;
        p.x += o.x; p.y += o.y; p.z += o.z; p.w += o.w;
        *(float4*)tp = p;
    }
}

// ---------------------------------------------------------------------------
extern "C" void kernel_launch(void* const* d_in, const int* in_sizes, int n_in,
                              void* d_out, int out_size, void* d_ws, size_t ws_size,
                              hipStream_t stream) {
    const float* x       = (const float*)d_in[0];
    const int*   src     = (const int*)d_in[1];
    const int*   dst     = (const int*)d_in[2];
    const float* Wk      = (const float*)d_in[3];
    const float* bk      = (const float*)d_in[4];
    const float* Wq      = (const float*)d_in[5];
    const float* bq      = (const float*)d_in[6];
    const float* Wv      = (const float*)d_in[7];
    const float* bv      = (const float*)d_in[8];
    const float* Wa      = (const float*)d_in[9];
    const float* ba      = (const float*)d_in[10];
    const float* rel_pri = (const float*)d_in[11];
    const float* rel_att = (const float*)d_in[12];
    const float* rel_msg = (const float*)d_in[13];
    const float* skip    = (const float*)d_in[14];
    float* out = (float*)d_out;
    char* ws = (char*)d_ws;

    const size_t ND = (size_t)NN * DD;
    size_t off = 0;
    unsigned short* q_bf   = (unsigned short*)(ws + off); off += ND * 2;              // 25.6MB
    float*          k      = (float*)(ws + off);          off += ND * 4;              // 51.2MB
    float*          v      = (float*)(ws + off);          off += ND * 4;              // 51.2MB
    unsigned short* tb_bf  = (unsigned short*)(ws + off); off += ND * 2;              // 25.6MB
    float*          tt     = (float*)(ws + off);          off += ND * 4;              // 51.2MB
    float*          expatt = (float*)(ws + off);          off += (size_t)EE * HH * 4; // 6.4MB
    int*            cnt    = (int*)(ws + off);            off += (size_t)NSEG * 4;
    int*            rowptr = (int*)(ws + off);            off += (size_t)(NSEG + 1) * 4;
    int*            cursor = (int*)(ws + off);            off += (size_t)NSEG * 4;
    int*            csr_src= (int*)(ws + off);            off += (size_t)2 * EE * 4;
    int*            csr_eid= (int*)(ws + off);            off += (size_t)2 * EE * 4;
    if (ws_size < off) return;  // visible failure if workspace too small

    // --- projections ---
    dim3 gg((NN + 63) / 64, DD / 64);
    sgemm_kernel<<<gg, 256, 0, stream>>>(x, Wq, bq, nullptr, q_bf, NN, nullptr, nullptr);
    sgemm_kernel<<<gg, 256, 0, stream>>>(x, Wk, bk, k, nullptr, NN, nullptr, nullptr);
    sgemm_kernel<<<gg, 256, 0, stream>>>(x, Wv, bv, v, nullptr, NN, nullptr, nullptr);

    // --- CSR build (overlaps projections on other CUs of the same stream order) ---
    hipMemsetAsync(cnt, 0, (size_t)NSEG * 4, stream);
    const int eg = (2 * EE + 255) / 256;
    count_kernel<<<eg, 256, 0, stream>>>(dst, cnt);
    scan_kernel<<<1, 1024, 0, stream>>>(cnt, rowptr);
    hipMemcpyAsync(cursor, rowptr, (size_t)NSEG * 4, hipMemcpyDeviceToDevice, stream);
    scatter_kernel<<<eg, 256, 0, stream>>>(src, dst, cursor, csr_src, csr_eid);

    // --- per relation: transform + attention + gather-aggregate ---
    const int tgrid = NN / 4;   // 12500
    const int egrid = EE / 8;   // 25000
    for (int r = 0; r < 2; ++r) {
        transform_kernel<<<tgrid, 256, 0, stream>>>(k, rel_att + (size_t)r * HH * DKK * DKK, tb_bf);
        edge_att_kernel<<<egrid, 256, 0, stream>>>(q_bf, tb_bf, src + (size_t)r * EE,
                                                   dst + (size_t)r * EE,
                                                   rel_pri + (size_t)r * HH, expatt);
        transform_kernel<<<tgrid, 256, 0, stream>>>(v, rel_msg + (size_t)r * HH * DKK * DKK, tb_bf);
        node_agg_kernel<<<tgrid, 256, 0, stream>>>(tb_bf, csr_src, csr_eid, rowptr, expatt, tt, r);
    }

    // --- output projection with skip gate ---
    sgemm_kernel<<<gg, 256, 0, stream>>>(tt, Wa, ba, out, nullptr, NN, x, skip);
}

// Round 4
// 924.514 us; speedup vs baseline: 3.8861x; 1.3620x over previous
//
#include <hip/hip_runtime.h>
#include <hip/hip_bf16.h>
#include <math.h>

#define NN 50000
#define EE 200000
#define DD 256
#define HH 8
#define DKK 32
#define NSEG (2 * NN)
#define SCAN_BLOCKS ((NSEG + 1023) / 1024)   // 98

constexpr float RSQRT_DK = 0.17677669529663687f;  // 1/sqrt(32)

__device__ __forceinline__ float bf_lo(unsigned u) { return __uint_as_float(u << 16); }
__device__ __forceinline__ float bf_hi(unsigned u) { return __uint_as_float(u & 0xffff0000u); }
__device__ __forceinline__ unsigned short f2bf(float f) {
    unsigned u = __float_as_uint(f);
    return (unsigned short)((u + 0x7fffu + ((u >> 16) & 1u)) >> 16);  // RNE
}

// ---------------------------------------------------------------------------
// SGEMM: C[nrows,256] = X[nrows,256] @ W[256,256] + bias (fp32 or bf16 out;
// optional skip-gate epilogue). 64x64 tile, BK=16, 4x4 micro-tile.
// ---------------------------------------------------------------------------
__global__ void sgemm_kernel(const float* __restrict__ X, const float* __restrict__ W,
                             const float* __restrict__ bias, float* __restrict__ C,
                             unsigned short* __restrict__ Cbf,
                             int nrows, const float* __restrict__ xres,
                             const float* __restrict__ skip) {
    __shared__ __align__(16) float As[16][64];
    __shared__ __align__(16) float Bs[16][64];
    const int t = threadIdx.x;
    const int row0 = blockIdx.x * 64, col0 = blockIdx.y * 64;
    const int tr = t >> 4, tc = t & 15;
    float acc[4][4] = {};

    const int ra  = row0 + (t >> 2);
    const int kk4 = (t & 3) << 2;

    for (int k0 = 0; k0 < 256; k0 += 16) {
        float4 a4 = make_float4(0.f, 0.f, 0.f, 0.f);
        if (ra < nrows) a4 = *(const float4*)&X[(size_t)ra * 256 + k0 + kk4];
        As[kk4 + 0][t >> 2] = a4.x;
        As[kk4 + 1][t >> 2] = a4.y;
        As[kk4 + 2][t >> 2] = a4.z;
        As[kk4 + 3][t >> 2] = a4.w;
        *(float4*)&Bs[t >> 4][(t & 15) << 2] =
            *(const float4*)&W[(size_t)(k0 + (t >> 4)) * 256 + col0 + ((t & 15) << 2)];
        __syncthreads();
        #pragma unroll
        for (int kk = 0; kk < 16; ++kk) {
            float4 av = *(const float4*)&As[kk][tr << 2];
            float4 bv = *(const float4*)&Bs[kk][tc << 2];
            acc[0][0] += av.x * bv.x; acc[0][1] += av.x * bv.y;
            acc[0][2] += av.x * bv.z; acc[0][3] += av.x * bv.w;
            acc[1][0] += av.y * bv.x; acc[1][1] += av.y * bv.y;
            acc[1][2] += av.y * bv.z; acc[1][3] += av.y * bv.w;
            acc[2][0] += av.z * bv.x; acc[2][1] += av.z * bv.y;
            acc[2][2] += av.z * bv.z; acc[2][3] += av.z * bv.w;
            acc[3][0] += av.w * bv.x; acc[3][1] += av.w * bv.y;
            acc[3][2] += av.w * bv.z; acc[3][3] += av.w * bv.w;
        }
        __syncthreads();
    }

    float alpha = 1.f, beta = 0.f;
    if (skip) { alpha = 1.f / (1.f + __expf(-skip[0])); beta = 1.f - alpha; }
    const int col = col0 + (tc << 2);
    #pragma unroll
    for (int i = 0; i < 4; ++i) {
        int row = row0 + (tr << 2) + i;
        if (row >= nrows) break;
        float4 o;
        o.x = acc[i][0] + bias[col + 0];
        o.y = acc[i][1] + bias[col + 1];
        o.z = acc[i][2] + bias[col + 2];
        o.w = acc[i][3] + bias[col + 3];
        if (xres) {
            float4 xr = *(const float4*)&xres[(size_t)row * 256 + col];
            o.x = o.x * alpha + xr.x * beta;
            o.y = o.y * alpha + xr.y * beta;
            o.z = o.z * alpha + xr.z * beta;
            o.w = o.w * alpha + xr.w * beta;
        }
        if (Cbf) {
            ushort4 ob;
            ob.x = f2bf(o.x); ob.y = f2bf(o.y); ob.z = f2bf(o.z); ob.w = f2bf(o.w);
            *(ushort4*)&Cbf[(size_t)row * 256 + col] = ob;
        } else {
            *(float4*)&C[(size_t)row * 256 + col] = o;
        }
    }
}

// ---------------------------------------------------------------------------
// Per-node head transform: out[n,h,f] = sum_d in[n,h,d] * A[h,d,f], bf16 out.
// ---------------------------------------------------------------------------
#define ASTRIDE 1028
__global__ void transform_kernel(const float* __restrict__ in, const float* __restrict__ A_g,
                                 unsigned short* __restrict__ out_bf) {
    __shared__ __align__(16) float A[HH * ASTRIDE];
    for (int i = threadIdx.x; i < HH * DKK * DKK; i += 256) {
        int h = i >> 10;
        A[h * ASTRIDE + (i & 1023)] = A_g[i];
    }
    __syncthreads();
    const int wave = threadIdx.x >> 6, lane = threadIdx.x & 63;
    const int h = lane >> 3, j = lane & 7;
    const int n = blockIdx.x * 4 + wave;  // grid = NN/4 exact

    float rbuf[32];
    const float* rowp = &in[(size_t)n * 256 + h * 32];
    #pragma unroll
    for (int c = 0; c < 8; ++c) *(float4*)&rbuf[c * 4] = *(const float4*)&rowp[c * 4];

    float4 acc = make_float4(0.f, 0.f, 0.f, 0.f);
    const float* Ah = &A[h * ASTRIDE + j * 4];
    #pragma unroll
    for (int d = 0; d < 32; ++d) {
        float rv = rbuf[d];
        float4 av = *(const float4*)&Ah[d * 32];
        acc.x += rv * av.x; acc.y += rv * av.y;
        acc.z += rv * av.z; acc.w += rv * av.w;
    }
    ushort4 ob;
    ob.x = f2bf(acc.x); ob.y = f2bf(acc.y); ob.z = f2bf(acc.z); ob.w = f2bf(acc.w);
    *(ushort4*)&out_bf[(size_t)n * 256 + h * 32 + j * 4] = ob;
}

// ---------------------------------------------------------------------------
// CSR build: count -> 3-phase multiblock scan -> scatter. Segment = r*NN + dst.
// ---------------------------------------------------------------------------
__global__ void count_kernel(const int* __restrict__ dst, int* __restrict__ cnt) {
    int e = blockIdx.x * 256 + threadIdx.x;
    if (e < 2 * EE) atomicAdd(&cnt[(e / EE) * NN + dst[e]], 1);
}

__global__ __launch_bounds__(1024) void scan_local_kernel(const int* __restrict__ cnt,
                                                          int* __restrict__ rowptr,
                                                          int* __restrict__ bsum) {
    __shared__ int sh[1024];
    const int t = threadIdx.x;
    const int idx = blockIdx.x * 1024 + t;
    const int c = (idx < NSEG) ? cnt[idx] : 0;
    sh[t] = c;
    __syncthreads();
    #pragma unroll
    for (int ofs = 1; ofs < 1024; ofs <<= 1) {   // Hillis-Steele inclusive
        int v = (t >= ofs) ? sh[t - ofs] : 0;
        __syncthreads();
        sh[t] += v;
        __syncthreads();
    }
    if (idx < NSEG) rowptr[idx] = sh[t] - c;     // exclusive within block
    if (t == 1023) bsum[blockIdx.x] = sh[1023];
}

__global__ void scan_bsum_kernel(int* __restrict__ bsum, int* __restrict__ rowptr) {
    __shared__ int sh[128];
    const int t = threadIdx.x;  // 128 threads, SCAN_BLOCKS=98 <= 128
    const int v = (t < SCAN_BLOCKS) ? bsum[t] : 0;
    sh[t] = v;
    __syncthreads();
    #pragma unroll
    for (int ofs = 1; ofs < 128; ofs <<= 1) {
        int u = (t >= ofs) ? sh[t - ofs] : 0;
        __syncthreads();
        sh[t] += u;
        __syncthreads();
    }
    if (t < SCAN_BLOCKS) bsum[t] = sh[t] - v;    // exclusive block offsets
    if (t == 127) rowptr[NSEG] = sh[127];        // grand total = 2*EE
}

__global__ __launch_bounds__(1024) void scan_add_kernel(int* __restrict__ rowptr,
                                                        const int* __restrict__ bsum) {
    const int idx = blockIdx.x * 1024 + threadIdx.x;
    if (idx < NSEG) rowptr[idx] += bsum[blockIdx.x];
}

__global__ void scatter_kernel(const int* __restrict__ src, const int* __restrict__ dst,
                               int* __restrict__ cursor, int* __restrict__ csr_src,
                               int* __restrict__ csr_eid) {
    int e = blockIdx.x * 256 + threadIdx.x;
    if (e >= 2 * EE) return;
    int r = e / EE;
    int seg = r * NN + dst[e];
    int pos = atomicAdd(&cursor[seg], 1);
    csr_src[pos] = src[e];
    csr_eid[pos] = e - r * EE;  // local edge id (expatt is per-relation)
}

// ---------------------------------------------------------------------------
// Pass A: expatt[e,h] = exp(dot(q[dst,h], kt[src,h]) * pri[h]/sqrt(dk)).
// 32 lanes/edge; max-pass skipped (att ~ N(0,1), softmax shift-invariant).
// ---------------------------------------------------------------------------
__global__ void edge_att_kernel(const unsigned short* __restrict__ q,
                                const unsigned short* __restrict__ kt,
                                const int* __restrict__ src, const int* __restrict__ dst,
                                const float* __restrict__ pri,
                                float* __restrict__ expatt) {
    const int half = threadIdx.x >> 5;
    const int ll = threadIdx.x & 31;
    const int h = ll >> 2, quad = ll & 3;
    const int e = blockIdx.x * 8 + half;
    const int s = src[e], d_ = dst[e];
    const size_t off = (size_t)(h * 32 + quad * 8);

    uint4 a = *(const uint4*)&q[(size_t)d_ * 256 + off];
    uint4 b = *(const uint4*)&kt[(size_t)s * 256 + off];
    float p = bf_lo(a.x) * bf_lo(b.x) + bf_hi(a.x) * bf_hi(b.x)
            + bf_lo(a.y) * bf_lo(b.y) + bf_hi(a.y) * bf_hi(b.y)
            + bf_lo(a.z) * bf_lo(b.z) + bf_hi(a.z) * bf_hi(b.z)
            + bf_lo(a.w) * bf_lo(b.w) + bf_hi(a.w) * bf_hi(b.w);
    p += __shfl_xor(p, 1);
    p += __shfl_xor(p, 2);
    if (quad == 0) {
        expatt[(size_t)e * HH + h] = __expf(p * pri[h] * RSQRT_DK);
    }
}

// ---------------------------------------------------------------------------
// Pass B (CSR gather, NO atomics): one wave per node. Lane owns 4 consecutive
// floats (head h = lane>>3). Accumulate num = sum e_i * vt[src_i], den = sum e_i
// over the node's incoming edges; tt[n] (+)= 0.5 * num/den. r=0 writes, r=1 adds.
// ---------------------------------------------------------------------------
__global__ void node_agg_kernel(const unsigned short* __restrict__ vt,
                                const int* __restrict__ csr_src,
                                const int* __restrict__ csr_eid,
                                const int* __restrict__ rowptr,
                                const float* __restrict__ expatt,
                                float* __restrict__ tt, int r) {
    const int wave = threadIdx.x >> 6, lane = threadIdx.x & 63;
    const int n = blockIdx.x * 4 + wave;  // grid = NN/4 exact
    const int h = lane >> 3;
    const int off = lane * 4;
    const int seg = r * NN + n;
    const int j0 = rowptr[seg], j1 = rowptr[seg + 1];

    float4 acc = make_float4(0.f, 0.f, 0.f, 0.f);
    float den = 0.f;
    for (int j = j0; j < j1; ++j) {
        const int s = csr_src[j];
        const int e = csr_eid[j];
        const float a = expatt[(size_t)e * HH + h];
        den += a;
        uint2 b = *(const uint2*)&vt[(size_t)s * 256 + off];
        acc.x += a * bf_lo(b.x);
        acc.y += a * bf_hi(b.x);
        acc.z += a * bf_lo(b.y);
        acc.w += a * bf_hi(b.y);
    }
    const float w = (den > 0.f) ? 0.5f / den : 0.f;
    float4 o = make_float4(acc.x * w, acc.y * w, acc.z * w, acc.w * w);
    float* tp = &tt[(size_t)n * 256 + off];
    if (r == 0) {
        *(float4*)tp = o;
    } else {
        float4 p = *(const float4*)tp;
        p.x += o.x; p.y += o.y; p.z += o.z; p.w += o.w;
        *(float4*)tp = p;
    }
}

// ---------------------------------------------------------------------------
extern "C" void kernel_launch(void* const* d_in, const int* in_sizes, int n_in,
                              void* d_out, int out_size, void* d_ws, size_t ws_size,
                              hipStream_t stream) {
    const float* x       = (const float*)d_in[0];
    const int*   src     = (const int*)d_in[1];
    const int*   dst     = (const int*)d_in[2];
    const float* Wk      = (const float*)d_in[3];
    const float* bk      = (const float*)d_in[4];
    const float* Wq      = (const float*)d_in[5];
    const float* bq      = (const float*)d_in[6];
    const float* Wv      = (const float*)d_in[7];
    const float* bv      = (const float*)d_in[8];
    const float* Wa      = (const float*)d_in[9];
    const float* ba      = (const float*)d_in[10];
    const float* rel_pri = (const float*)d_in[11];
    const float* rel_att = (const float*)d_in[12];
    const float* rel_msg = (const float*)d_in[13];
    const float* skip    = (const float*)d_in[14];
    float* out = (float*)d_out;
    char* ws = (char*)d_ws;

    const size_t ND = (size_t)NN * DD;
    size_t off = 0;
    unsigned short* q_bf   = (unsigned short*)(ws + off); off += ND * 2;              // 25.6MB
    float*          k      = (float*)(ws + off);          off += ND * 4;              // 51.2MB
    float*          v      = (float*)(ws + off);          off += ND * 4;              // 51.2MB
    unsigned short* tb_bf  = (unsigned short*)(ws + off); off += ND * 2;              // 25.6MB
    float*          tt     = (float*)(ws + off);          off += ND * 4;              // 51.2MB
    float*          expatt = (float*)(ws + off);          off += (size_t)EE * HH * 4; // 6.4MB
    int*            cnt    = (int*)(ws + off);            off += (size_t)NSEG * 4;
    int*            rowptr = (int*)(ws + off);            off += (size_t)(NSEG + 1) * 4;
    int*            cursor = (int*)(ws + off);            off += (size_t)NSEG * 4;
    int*            bsum   = (int*)(ws + off);            off += (size_t)128 * 4;
    int*            csr_src= (int*)(ws + off);            off += (size_t)2 * EE * 4;
    int*            csr_eid= (int*)(ws + off);            off += (size_t)2 * EE * 4;
    if (ws_size < off) return;  // visible failure if workspace too small

    // --- projections ---
    dim3 gg((NN + 63) / 64, DD / 64);
    sgemm_kernel<<<gg, 256, 0, stream>>>(x, Wq, bq, nullptr, q_bf, NN, nullptr, nullptr);
    sgemm_kernel<<<gg, 256, 0, stream>>>(x, Wk, bk, k, nullptr, NN, nullptr, nullptr);
    sgemm_kernel<<<gg, 256, 0, stream>>>(x, Wv, bv, v, nullptr, NN, nullptr, nullptr);

    // --- CSR build ---
    hipMemsetAsync(cnt, 0, (size_t)NSEG * 4, stream);
    const int eg = (2 * EE + 255) / 256;
    count_kernel<<<eg, 256, 0, stream>>>(dst, cnt);
    scan_local_kernel<<<SCAN_BLOCKS, 1024, 0, stream>>>(cnt, rowptr, bsum);
    scan_bsum_kernel<<<1, 128, 0, stream>>>(bsum, rowptr);
    scan_add_kernel<<<SCAN_BLOCKS, 1024, 0, stream>>>(rowptr, bsum);
    hipMemcpyAsync(cursor, rowptr, (size_t)NSEG * 4, hipMemcpyDeviceToDevice, stream);
    scatter_kernel<<<eg, 256, 0, stream>>>(src, dst, cursor, csr_src, csr_eid);

    // --- per relation: transform + attention + gather-aggregate ---
    const int tgrid = NN / 4;   // 12500
    const int egrid = EE / 8;   // 25000
    for (int r = 0; r < 2; ++r) {
        transform_kernel<<<tgrid, 256, 0, stream>>>(k, rel_att + (size_t)r * HH * DKK * DKK, tb_bf);
        edge_att_kernel<<<egrid, 256, 0, stream>>>(q_bf, tb_bf, src + (size_t)r * EE,
                                                   dst + (size_t)r * EE,
                                                   rel_pri + (size_t)r * HH, expatt);
        transform_kernel<<<tgrid, 256, 0, stream>>>(v, rel_msg + (size_t)r * HH * DKK * DKK, tb_bf);
        node_agg_kernel<<<tgrid, 256, 0, stream>>>(tb_bf, csr_src, csr_eid, rowptr, expatt, tt, r);
    }

    // --- output projection with skip gate ---
    sgemm_kernel<<<gg, 256, 0, stream>>>(tt, Wa, ba, out, nullptr, NN, x, skip);
}

// Round 5
// 666.824 us; speedup vs baseline: 5.3879x; 1.3864x over previous
//
#include <hip/hip_runtime.h>
#include <hip/hip_bf16.h>
#include <math.h>

#define NN 50000
#define EE 200000
#define DD 256
#define HH 8
#define DKK 32
#define NSEG (2 * NN)
#define SCAN_BLOCKS ((NSEG + 1023) / 1024)   // 98
#define MPAD 50048                            // NN rounded up to 128-tile

constexpr float RSQRT_DK = 0.17677669529663687f;  // 1/sqrt(32)

__device__ __forceinline__ float bf_lo(unsigned u) { return __uint_as_float(u << 16); }
__device__ __forceinline__ float bf_hi(unsigned u) { return __uint_as_float(u & 0xffff0000u); }
__device__ __forceinline__ unsigned short f2bf(float f) {
    unsigned u = __float_as_uint(f);
    return (unsigned short)((u + 0x7fffu + ((u >> 16) & 1u)) >> 16);  // RNE
}

typedef __attribute__((ext_vector_type(8))) short bf16x8;
typedef __attribute__((ext_vector_type(4))) float f32x4;

#define GLDS16(g, l)                                                                   \
    __builtin_amdgcn_global_load_lds((const __attribute__((address_space(1))) unsigned int*)(g), \
                                     (__attribute__((address_space(3))) unsigned int*)(l), 16, 0, 0)

// ---------------------------------------------------------------------------
// Casts
// ---------------------------------------------------------------------------
__global__ void cast_x_kernel(const float* __restrict__ x, unsigned short* __restrict__ xb) {
    const size_t i = ((size_t)blockIdx.x * 256 + threadIdx.x) * 4;  // grid covers NN*DD/4
    float4 v = *(const float4*)&x[i];
    ushort4 o;
    o.x = f2bf(v.x); o.y = f2bf(v.y); o.z = f2bf(v.z); o.w = f2bf(v.w);
    *(ushort4*)&xb[i] = o;
}

// Bt[768][256] = [Wq|Wk|Wv] columns transposed; bb[768] = [bq|bk|bv]
__global__ void cast_wqkv_kernel(const float* __restrict__ Wq, const float* __restrict__ Wk,
                                 const float* __restrict__ Wv, const float* __restrict__ bq,
                                 const float* __restrict__ bk, const float* __restrict__ bv,
                                 unsigned short* __restrict__ Bt, float* __restrict__ bb) {
    const int n = blockIdx.x, kk = threadIdx.x;  // 768 x 256
    const float* W = (n < 256) ? Wq : (n < 512) ? Wk : Wv;
    const int nc = n & 255;
    Bt[(size_t)n * 256 + kk] = f2bf(W[(size_t)kk * 256 + nc]);
    if (kk == 0) bb[n] = (n < 256) ? bq[nc] : (n < 512) ? bk[nc] : bv[nc];
}

__global__ void cast_wa_kernel(const float* __restrict__ Wa, unsigned short* __restrict__ Bt) {
    const int n = blockIdx.x, kk = threadIdx.x;  // 256 x 256
    Bt[(size_t)n * 256 + kk] = f2bf(Wa[(size_t)kk * 256 + n]);
}

// ---------------------------------------------------------------------------
// MFMA bf16 GEMM: C[M,N] = A[M,256] @ Bt[N,256]^T + bias.
// 128x128 tile, BK=32, 256 thr (4 waves 2x2), 16x16x32 MFMA, fragment-ordered
// LDS via global_load_lds (lane-order write AND read -> zero bank conflicts).
// Cbf: bf16 out (ldc).  Cf: fp32 out with skip-gate epilogue (ldc=256).
// ---------------------------------------------------------------------------
__global__ void mfma_gemm(const unsigned short* __restrict__ A,
                          const unsigned short* __restrict__ Bt,
                          const float* __restrict__ bias,
                          unsigned short* __restrict__ Cbf, float* __restrict__ Cf,
                          int M, int ldc,
                          const float* __restrict__ xres, const float* __restrict__ skip) {
    __shared__ __align__(16) unsigned short As[8][64][8];  // [16-row chunk][lane][8 bf16]
    __shared__ __align__(16) unsigned short Bs[8][64][8];
    const int t = threadIdx.x;
    const int w = t >> 6, l = t & 63;
    const int m0 = blockIdx.x * 128, n0 = blockIdx.y * 128;
    const int wm = w & 1, wn = w >> 1;

    // staging: wave w loads A chunks {w,w+4}, B chunks {w,w+4};
    // lane l -> row chunk*16 + (l&15), k-quad l>>4 (matches MFMA A/B frag order)
    const int sr = l & 15, sq = l >> 4;
    const unsigned short* ga0 = A  + (size_t)(m0 + w * 16 + sr) * 256 + sq * 8;
    const unsigned short* ga1 = A  + (size_t)(m0 + (w + 4) * 16 + sr) * 256 + sq * 8;
    const unsigned short* gb0 = Bt + (size_t)(n0 + w * 16 + sr) * 256 + sq * 8;
    const unsigned short* gb1 = Bt + (size_t)(n0 + (w + 4) * 16 + sr) * 256 + sq * 8;

    f32x4 acc[4][4];
    #pragma unroll
    for (int mi = 0; mi < 4; ++mi)
        #pragma unroll
        for (int ni = 0; ni < 4; ++ni) acc[mi][ni] = (f32x4){0.f, 0.f, 0.f, 0.f};

    for (int k0 = 0; k0 < 256; k0 += 32) {
        GLDS16(ga0 + k0, &As[w][0][0]);
        GLDS16(ga1 + k0, &As[w + 4][0][0]);
        GLDS16(gb0 + k0, &Bs[w][0][0]);
        GLDS16(gb1 + k0, &Bs[w + 4][0][0]);
        __syncthreads();
        bf16x8 af[4], bfr[4];
        #pragma unroll
        for (int i = 0; i < 4; ++i) {
            af[i]  = *(const bf16x8*)&As[wm * 4 + i][l][0];
            bfr[i] = *(const bf16x8*)&Bs[wn * 4 + i][l][0];
        }
        #pragma unroll
        for (int mi = 0; mi < 4; ++mi)
            #pragma unroll
            for (int ni = 0; ni < 4; ++ni)
                acc[mi][ni] = __builtin_amdgcn_mfma_f32_16x16x32_bf16(af[mi], bfr[ni],
                                                                      acc[mi][ni], 0, 0, 0);
        __syncthreads();
    }

    // epilogue: C/D layout col=lane&15, row=(lane>>4)*4+reg
    float alpha = 1.f, beta = 0.f;
    if (skip) { alpha = 1.f / (1.f + __expf(-skip[0])); beta = 1.f - alpha; }
    const int q4 = l >> 4, c15 = l & 15;
    #pragma unroll
    for (int ni = 0; ni < 4; ++ni) {
        const int col = n0 + wn * 64 + ni * 16 + c15;
        const float bcol = bias[col];
        #pragma unroll
        for (int mi = 0; mi < 4; ++mi) {
            const int rbase = m0 + wm * 64 + mi * 16 + q4 * 4;
            #pragma unroll
            for (int p = 0; p < 4; ++p) {
                const int row = rbase + p;
                if (row < M) {
                    const float o = acc[mi][ni][p] + bcol;
                    if (Cf) {
                        const float xr = xres[(size_t)row * 256 + col];
                        Cf[(size_t)row * 256 + col] = o * alpha + xr * beta;
                    } else {
                        Cbf[(size_t)row * (size_t)ldc + col] = f2bf(o);
                    }
                }
            }
        }
    }
}

// ---------------------------------------------------------------------------
// Per-node head transform: out[n,h,f] = sum_d in[n,h,d] * A[h,d,f]; bf16 in/out.
// ---------------------------------------------------------------------------
#define ASTRIDE 1028
__global__ void transform_kernel(const unsigned short* __restrict__ in, int ldin,
                                 const float* __restrict__ A_g,
                                 unsigned short* __restrict__ out_bf) {
    __shared__ __align__(16) float A[HH * ASTRIDE];
    for (int i = threadIdx.x; i < HH * DKK * DKK; i += 256) {
        int h = i >> 10;
        A[h * ASTRIDE + (i & 1023)] = A_g[i];
    }
    __syncthreads();
    const int wave = threadIdx.x >> 6, lane = threadIdx.x & 63;
    const int h = lane >> 3, j = lane & 7;
    const int n = blockIdx.x * 4 + wave;  // grid = NN/4 exact

    float rbuf[32];
    const unsigned short* rowp = &in[(size_t)n * ldin + h * 32];
    #pragma unroll
    for (int c = 0; c < 4; ++c) {
        uint4 u = *(const uint4*)&rowp[c * 8];
        rbuf[c * 8 + 0] = bf_lo(u.x); rbuf[c * 8 + 1] = bf_hi(u.x);
        rbuf[c * 8 + 2] = bf_lo(u.y); rbuf[c * 8 + 3] = bf_hi(u.y);
        rbuf[c * 8 + 4] = bf_lo(u.z); rbuf[c * 8 + 5] = bf_hi(u.z);
        rbuf[c * 8 + 6] = bf_lo(u.w); rbuf[c * 8 + 7] = bf_hi(u.w);
    }

    float4 acc = make_float4(0.f, 0.f, 0.f, 0.f);
    const float* Ah = &A[h * ASTRIDE + j * 4];
    #pragma unroll
    for (int d = 0; d < 32; ++d) {
        float rv = rbuf[d];
        float4 av = *(const float4*)&Ah[d * 32];
        acc.x += rv * av.x; acc.y += rv * av.y;
        acc.z += rv * av.z; acc.w += rv * av.w;
    }
    ushort4 ob;
    ob.x = f2bf(acc.x); ob.y = f2bf(acc.y); ob.z = f2bf(acc.z); ob.w = f2bf(acc.w);
    *(ushort4*)&out_bf[(size_t)n * 256 + h * 32 + j * 4] = ob;
}

// ---------------------------------------------------------------------------
// CSR build: count -> 3-phase multiblock scan -> scatter. Segment = r*NN + dst.
// ---------------------------------------------------------------------------
__global__ void count_kernel(const int* __restrict__ dst, int* __restrict__ cnt) {
    int e = blockIdx.x * 256 + threadIdx.x;
    if (e < 2 * EE) atomicAdd(&cnt[(e / EE) * NN + dst[e]], 1);
}

__global__ __launch_bounds__(1024) void scan_local_kernel(const int* __restrict__ cnt,
                                                          int* __restrict__ rowptr,
                                                          int* __restrict__ bsum) {
    __shared__ int sh[1024];
    const int t = threadIdx.x;
    const int idx = blockIdx.x * 1024 + t;
    const int c = (idx < NSEG) ? cnt[idx] : 0;
    sh[t] = c;
    __syncthreads();
    #pragma unroll
    for (int ofs = 1; ofs < 1024; ofs <<= 1) {
        int v = (t >= ofs) ? sh[t - ofs] : 0;
        __syncthreads();
        sh[t] += v;
        __syncthreads();
    }
    if (idx < NSEG) rowptr[idx] = sh[t] - c;
    if (t == 1023) bsum[blockIdx.x] = sh[1023];
}

__global__ void scan_bsum_kernel(int* __restrict__ bsum, int* __restrict__ rowptr) {
    __shared__ int sh[128];
    const int t = threadIdx.x;
    const int v = (t < SCAN_BLOCKS) ? bsum[t] : 0;
    sh[t] = v;
    __syncthreads();
    #pragma unroll
    for (int ofs = 1; ofs < 128; ofs <<= 1) {
        int u = (t >= ofs) ? sh[t - ofs] : 0;
        __syncthreads();
        sh[t] += u;
        __syncthreads();
    }
    if (t < SCAN_BLOCKS) bsum[t] = sh[t] - v;
    if (t == 127) rowptr[NSEG] = sh[127];
}

__global__ __launch_bounds__(1024) void scan_add_kernel(int* __restrict__ rowptr,
                                                        const int* __restrict__ bsum) {
    const int idx = blockIdx.x * 1024 + threadIdx.x;
    if (idx < NSEG) rowptr[idx] += bsum[blockIdx.x];
}

__global__ void scatter_kernel(const int* __restrict__ src, const int* __restrict__ dst,
                               int* __restrict__ cursor, int* __restrict__ csr_src,
                               int* __restrict__ csr_eid) {
    int e = blockIdx.x * 256 + threadIdx.x;
    if (e >= 2 * EE) return;
    int r = e / EE;
    int seg = r * NN + dst[e];
    int pos = atomicAdd(&cursor[seg], 1);
    csr_src[pos] = src[e];
    csr_eid[pos] = e - r * EE;
}

// ---------------------------------------------------------------------------
// Pass A: expatt[e,h] = exp(dot(q[dst,h], kt[src,h]) * pri[h]/sqrt(dk)).
// ---------------------------------------------------------------------------
__global__ void edge_att_kernel(const unsigned short* __restrict__ q, int ldq,
                                const unsigned short* __restrict__ kt,
                                const int* __restrict__ src, const int* __restrict__ dst,
                                const float* __restrict__ pri,
                                float* __restrict__ expatt) {
    const int half = threadIdx.x >> 5;
    const int ll = threadIdx.x & 31;
    const int h = ll >> 2, quad = ll & 3;
    const int e = blockIdx.x * 8 + half;
    const int s = src[e], d_ = dst[e];
    const size_t off = (size_t)(h * 32 + quad * 8);

    uint4 a = *(const uint4*)&q[(size_t)d_ * ldq + off];
    uint4 b = *(const uint4*)&kt[(size_t)s * 256 + off];
    float p = bf_lo(a.x) * bf_lo(b.x) + bf_hi(a.x) * bf_hi(b.x)
            + bf_lo(a.y) * bf_lo(b.y) + bf_hi(a.y) * bf_hi(b.y)
            + bf_lo(a.z) * bf_lo(b.z) + bf_hi(a.z) * bf_hi(b.z)
            + bf_lo(a.w) * bf_lo(b.w) + bf_hi(a.w) * bf_hi(b.w);
    p += __shfl_xor(p, 1);
    p += __shfl_xor(p, 2);
    if (quad == 0) {
        expatt[(size_t)e * HH + h] = __expf(p * pri[h] * RSQRT_DK);
    }
}

// ---------------------------------------------------------------------------
// Pass B (CSR gather): one wave per node. r=0 -> write fp32 tt; r=1 -> read tt,
// add, write bf16 tt_bf (feeds output MFMA GEMM directly).
// ---------------------------------------------------------------------------
__global__ void node_agg_kernel(const unsigned short* __restrict__ vt,
                                const int* __restrict__ csr_src,
                                const int* __restrict__ csr_eid,
                                const int* __restrict__ rowptr,
                                const float* __restrict__ expatt,
                                float* __restrict__ tt,
                                unsigned short* __restrict__ tt_bf, int r) {
    const int wave = threadIdx.x >> 6, lane = threadIdx.x & 63;
    const int n = blockIdx.x * 4 + wave;
    const int h = lane >> 3;
    const int off = lane * 4;
    const int seg = r * NN + n;
    const int j0 = rowptr[seg], j1 = rowptr[seg + 1];

    float4 acc = make_float4(0.f, 0.f, 0.f, 0.f);
    float den = 0.f;
    for (int j = j0; j < j1; ++j) {
        const int s = csr_src[j];
        const int e = csr_eid[j];
        const float a = expatt[(size_t)e * HH + h];
        den += a;
        uint2 b = *(const uint2*)&vt[(size_t)s * 256 + off];
        acc.x += a * bf_lo(b.x);
        acc.y += a * bf_hi(b.x);
        acc.z += a * bf_lo(b.y);
        acc.w += a * bf_hi(b.y);
    }
    const float w = (den > 0.f) ? 0.5f / den : 0.f;
    float4 o = make_float4(acc.x * w, acc.y * w, acc.z * w, acc.w * w);
    if (r == 0) {
        *(float4*)&tt[(size_t)n * 256 + off] = o;
    } else {
        float4 p = *(const float4*)&tt[(size_t)n * 256 + off];
        ushort4 ob;
        ob.x = f2bf(p.x + o.x); ob.y = f2bf(p.y + o.y);
        ob.z = f2bf(p.z + o.z); ob.w = f2bf(p.w + o.w);
        *(ushort4*)&tt_bf[(size_t)n * 256 + off] = ob;
    }
}

// ---------------------------------------------------------------------------
extern "C" void kernel_launch(void* const* d_in, const int* in_sizes, int n_in,
                              void* d_out, int out_size, void* d_ws, size_t ws_size,
                              hipStream_t stream) {
    const float* x       = (const float*)d_in[0];
    const int*   src     = (const int*)d_in[1];
    const int*   dst     = (const int*)d_in[2];
    const float* Wk      = (const float*)d_in[3];
    const float* bk      = (const float*)d_in[4];
    const float* Wq      = (const float*)d_in[5];
    const float* bq      = (const float*)d_in[6];
    const float* Wv      = (const float*)d_in[7];
    const float* bv      = (const float*)d_in[8];
    const float* Wa      = (const float*)d_in[9];
    const float* ba      = (const float*)d_in[10];
    const float* rel_pri = (const float*)d_in[11];
    const float* rel_att = (const float*)d_in[12];
    const float* rel_msg = (const float*)d_in[13];
    const float* skip    = (const float*)d_in[14];
    float* out = (float*)d_out;
    char* ws = (char*)d_ws;

    const size_t ND  = (size_t)NN * DD;
    const size_t NDP = (size_t)MPAD * DD;   // padded rows for GEMM edge-tiles
    size_t off = 0;
    unsigned short* x_bf   = (unsigned short*)(ws + off); off += NDP * 2;                  // 25.6MB
    unsigned short* qkv_bf = (unsigned short*)(ws + off); off += (size_t)NN * 768 * 2;     // 76.8MB
    unsigned short* tb_bf  = (unsigned short*)(ws + off); off += ND * 2;                   // 25.6MB
    float*          tt     = (float*)(ws + off);          off += ND * 4;                   // 51.2MB
    unsigned short* tt_bf  = (unsigned short*)(ws + off); off += NDP * 2;                  // 25.6MB
    float*          expatt = (float*)(ws + off);          off += (size_t)EE * HH * 4;      // 6.4MB
    unsigned short* wqkv_t = (unsigned short*)(ws + off); off += (size_t)768 * 256 * 2;
    unsigned short* wa_t   = (unsigned short*)(ws + off); off += (size_t)256 * 256 * 2;
    float*          bb     = (float*)(ws + off);          off += 768 * 4;
    int*            cnt    = (int*)(ws + off);            off += (size_t)NSEG * 4;
    int*            rowptr = (int*)(ws + off);            off += (size_t)(NSEG + 1) * 4;
    int*            cursor = (int*)(ws + off);            off += (size_t)NSEG * 4;
    int*            bsum   = (int*)(ws + off);            off += 128 * 4;
    int*            csr_src= (int*)(ws + off);            off += (size_t)2 * EE * 4;
    int*            csr_eid= (int*)(ws + off);            off += (size_t)2 * EE * 4;
    if (ws_size < off) return;

    // --- casts ---
    cast_x_kernel<<<(int)(ND / 1024), 256, 0, stream>>>(x, x_bf);
    cast_wqkv_kernel<<<768, 256, 0, stream>>>(Wq, Wk, Wv, bq, bk, bv, wqkv_t, bb);
    cast_wa_kernel<<<256, 256, 0, stream>>>(Wa, wa_t);

    // --- fused QKV projection: qkv[50000,768] bf16 ---
    dim3 g_qkv((MPAD / 128), 768 / 128);
    mfma_gemm<<<g_qkv, 256, 0, stream>>>(x_bf, wqkv_t, bb, qkv_bf, nullptr,
                                         NN, 768, nullptr, nullptr);

    // --- CSR build ---
    hipMemsetAsync(cnt, 0, (size_t)NSEG * 4, stream);
    const int eg = (2 * EE + 255) / 256;
    count_kernel<<<eg, 256, 0, stream>>>(dst, cnt);
    scan_local_kernel<<<SCAN_BLOCKS, 1024, 0, stream>>>(cnt, rowptr, bsum);
    scan_bsum_kernel<<<1, 128, 0, stream>>>(bsum, rowptr);
    scan_add_kernel<<<SCAN_BLOCKS, 1024, 0, stream>>>(rowptr, bsum);
    hipMemcpyAsync(cursor, rowptr, (size_t)NSEG * 4, hipMemcpyDeviceToDevice, stream);
    scatter_kernel<<<eg, 256, 0, stream>>>(src, dst, cursor, csr_src, csr_eid);

    // --- per relation: transform + attention + gather-aggregate ---
    const int tgrid = NN / 4;   // 12500
    const int egrid = EE / 8;   // 25000
    for (int r = 0; r < 2; ++r) {
        transform_kernel<<<tgrid, 256, 0, stream>>>(qkv_bf + 256, 768,
                                                    rel_att + (size_t)r * HH * DKK * DKK, tb_bf);
        edge_att_kernel<<<egrid, 256, 0, stream>>>(qkv_bf, 768, tb_bf,
                                                   src + (size_t)r * EE, dst + (size_t)r * EE,
                                                   rel_pri + (size_t)r * HH, expatt);
        transform_kernel<<<tgrid, 256, 0, stream>>>(qkv_bf + 512, 768,
                                                    rel_msg + (size_t)r * HH * DKK * DKK, tb_bf);
        node_agg_kernel<<<tgrid, 256, 0, stream>>>(tb_bf, csr_src, csr_eid, rowptr,
                                                   expatt, tt, tt_bf, r);
    }

    // --- output projection with skip gate (fp32 out) ---
    dim3 g_out((MPAD / 128), 256 / 128);
    mfma_gemm<<<g_out, 256, 0, stream>>>(tt_bf, wa_t, ba, nullptr, out,
                                         NN, 256, x, skip);
}

// Round 6
// 435.217 us; speedup vs baseline: 8.2551x; 1.5322x over previous
//
#include <hip/hip_runtime.h>
#include <hip/hip_bf16.h>
#include <math.h>

#define NN 50000
#define EE 200000
#define DD 256
#define HH 8
#define DKK 32
#define NSEG (2 * NN)
#define SCAN_BLOCKS ((NSEG + 1023) / 1024)   // 98
#define MPAD 50048                            // NN rounded up to 128-tile
#define LDQKV 1280                            // q | kt0 | kt1 | vt0 | vt1

constexpr float RSQRT_DK = 0.17677669529663687f;  // 1/sqrt(32)

__device__ __forceinline__ float bf_lo(unsigned u) { return __uint_as_float(u << 16); }
__device__ __forceinline__ float bf_hi(unsigned u) { return __uint_as_float(u & 0xffff0000u); }
__device__ __forceinline__ unsigned short f2bf(float f) {
    unsigned u = __float_as_uint(f);
    return (unsigned short)((u + 0x7fffu + ((u >> 16) & 1u)) >> 16);  // RNE
}

typedef __attribute__((ext_vector_type(8))) short bf16x8;
typedef __attribute__((ext_vector_type(4))) float f32x4;

#define GLDS16(g, l)                                                                   \
    __builtin_amdgcn_global_load_lds((const __attribute__((address_space(1))) unsigned int*)(g), \
                                     (__attribute__((address_space(3))) unsigned int*)(l), 16, 0, 0)

// ---------------------------------------------------------------------------
// Casts / weight folds
// ---------------------------------------------------------------------------
__global__ void cast_x_kernel(const float* __restrict__ x, unsigned short* __restrict__ xb) {
    const size_t i = ((size_t)blockIdx.x * 256 + threadIdx.x) * 4;  // grid covers NN*DD/4
    float4 v = *(const float4*)&x[i];
    ushort4 o;
    o.x = f2bf(v.x); o.y = f2bf(v.y); o.z = f2bf(v.z); o.w = f2bf(v.w);
    *(ushort4*)&xb[i] = o;
}

// Wt[1280][256]: col n of fused projection, transposed.
// n<256: Wq col n.  sec=(n-256)>>8: 0,1 -> Wk @ rel_att[r];  2,3 -> Wv @ rel_msg[r].
__global__ void fold_qkv_kernel(const float* __restrict__ Wq, const float* __restrict__ Wk,
                                const float* __restrict__ Wv, const float* __restrict__ bq,
                                const float* __restrict__ bk, const float* __restrict__ bv,
                                const float* __restrict__ rel_att, const float* __restrict__ rel_msg,
                                unsigned short* __restrict__ Wt, float* __restrict__ bb) {
    const int n = blockIdx.x, kk = threadIdx.x;
    if (n < 256) {
        Wt[(size_t)n * 256 + kk] = f2bf(Wq[(size_t)kk * 256 + n]);
        if (kk == 0) bb[n] = bq[n];
        return;
    }
    const int sec = (n - 256) >> 8;       // 0..3
    const int c = (n - 256) & 255;
    const int h = c >> 5, f = c & 31;
    const float* W    = (sec < 2) ? Wk : Wv;
    const float* bsrc = (sec < 2) ? bk : bv;
    const float* T = ((sec < 2) ? rel_att : rel_msg)
                   + (size_t)(sec & 1) * HH * DKK * DKK + (size_t)h * DKK * DKK + f;
    const float* wrow = &W[(size_t)kk * 256 + h * 32];
    float s = 0.f;
    #pragma unroll
    for (int d = 0; d < 32; ++d) s += wrow[d] * T[(size_t)d * 32];
    Wt[(size_t)n * 256 + kk] = f2bf(s);
    if (kk == 0) {
        float sb = 0.f;
        for (int d = 0; d < 32; ++d) sb += bsrc[h * 32 + d] * T[(size_t)d * 32];
        bb[n] = sb;
    }
}

__global__ void cast_wa_kernel(const float* __restrict__ Wa, unsigned short* __restrict__ Bt) {
    const int n = blockIdx.x, kk = threadIdx.x;  // 256 x 256
    Bt[(size_t)n * 256 + kk] = f2bf(Wa[(size_t)kk * 256 + n]);
}

// ---------------------------------------------------------------------------
// MFMA bf16 GEMM: C[M,N] = A[M,256] @ Bt[N,256]^T + bias.
// 128x128 tile, BK=32, 256 thr (4 waves 2x2), double-buffered LDS, ONE barrier
// per K-iter with post-barrier prefetch. Epilogue transposes through the
// (reused) staging LDS for vectorized coalesced stores.
// Cbf: bf16 out (ldc).  Cf: fp32 out + skip-gate epilogue (ldc=256).
// grid: (N/128, M/128)  -> consecutive blocks share the A panel.
// ---------------------------------------------------------------------------
__global__ __launch_bounds__(256) void mfma_gemm(
        const unsigned short* __restrict__ A, const unsigned short* __restrict__ Bt,
        const float* __restrict__ bias,
        unsigned short* __restrict__ Cbf, float* __restrict__ Cf,
        int M, int ldc, const float* __restrict__ xres, const float* __restrict__ skip) {
    __shared__ __align__(16) unsigned short As[2][8][64][8];  // 16KB
    __shared__ __align__(16) unsigned short Bs[2][8][64][8];  // 16KB
    const int t = threadIdx.x;
    const int w = t >> 6, l = t & 63;
    const int n0 = blockIdx.x * 128, m0 = blockIdx.y * 128;
    const int wm = w & 1, wn = w >> 1;

    const int sr = l & 15, sq = l >> 4;
    const unsigned short* ga0 = A  + (size_t)(m0 + w * 16 + sr) * 256 + sq * 8;
    const unsigned short* ga1 = A  + (size_t)(m0 + (w + 4) * 16 + sr) * 256 + sq * 8;
    const unsigned short* gb0 = Bt + (size_t)(n0 + w * 16 + sr) * 256 + sq * 8;
    const unsigned short* gb1 = Bt + (size_t)(n0 + (w + 4) * 16 + sr) * 256 + sq * 8;

#define STAGE(buf, k0) do {                    \
        GLDS16(ga0 + (k0), &As[buf][w][0][0]); \
        GLDS16(ga1 + (k0), &As[buf][w + 4][0][0]); \
        GLDS16(gb0 + (k0), &Bs[buf][w][0][0]); \
        GLDS16(gb1 + (k0), &Bs[buf][w + 4][0][0]); } while (0)

    f32x4 acc[4][4];
    #pragma unroll
    for (int mi = 0; mi < 4; ++mi)
        #pragma unroll
        for (int ni = 0; ni < 4; ++ni) acc[mi][ni] = (f32x4){0.f, 0.f, 0.f, 0.f};

    STAGE(0, 0);
    #pragma unroll
    for (int it = 0; it < 8; ++it) {
        __syncthreads();                       // staged buf (it&1) ready; prior reads done
        if (it < 7) {
            const int nb = (it + 1) & 1, nk = (it + 1) * 32;
            STAGE(nb, nk);                     // overlaps this iter's ds_read+MFMA
        }
        const int b = it & 1;
        bf16x8 af[4], bfr[4];
        #pragma unroll
        for (int i = 0; i < 4; ++i) {
            af[i]  = *(const bf16x8*)&As[b][wm * 4 + i][l][0];
            bfr[i] = *(const bf16x8*)&Bs[b][wn * 4 + i][l][0];
        }
        #pragma unroll
        for (int mi = 0; mi < 4; ++mi)
            #pragma unroll
            for (int ni = 0; ni < 4; ++ni)
                acc[mi][ni] = __builtin_amdgcn_mfma_f32_16x16x32_bf16(af[mi], bfr[ni],
                                                                      acc[mi][ni], 0, 0, 0);
    }
    __syncthreads();  // all LDS reads done; staging LDS now reused by epilogue

    // per-wave 8KB LDS region for transpose (waves 0,1 in As; 2,3 in Bs)
    unsigned short* ep = (w < 2) ? &As[0][0][0][0] : &Bs[0][0][0][0];
    ep += (w & 1) * 4096;
    const int q4 = l >> 4, c15 = l & 15;

    if (Cf == nullptr) {
        // ---- bf16 path: stage 64x64 ushort, store uint4 (8 rows x 128B per instr)
        #pragma unroll
        for (int ni = 0; ni < 4; ++ni) {
            const float bcol = bias[n0 + wn * 64 + ni * 16 + c15];
            #pragma unroll
            for (int mi = 0; mi < 4; ++mi)
                #pragma unroll
                for (int p = 0; p < 4; ++p)
                    ep[(mi * 16 + q4 * 4 + p) * 64 + ni * 16 + c15] =
                        f2bf(acc[mi][ni][p] + bcol);
        }
        __syncthreads();
        const int rs = l >> 3, cc = l & 7;
        #pragma unroll
        for (int i = 0; i < 8; ++i) {
            const int rl = i * 8 + rs;
            const int row = m0 + wm * 64 + rl;
            if (row < M) {
                uint4 v = *(const uint4*)&ep[rl * 64 + cc * 8];
                *(uint4*)&Cbf[(size_t)row * (size_t)ldc + n0 + wn * 64 + cc * 8] = v;
            }
        }
    } else {
        // ---- fp32 + skip path: two passes of 32 rows, float4 stores
        const float alpha = 1.f / (1.f + __expf(-skip[0]));
        const float beta = 1.f - alpha;
        float* epf = (float*)ep;   // 2048 floats = 32 x 64
        #pragma unroll
        for (int half = 0; half < 2; ++half) {
            __syncthreads();
            #pragma unroll
            for (int mi2 = 0; mi2 < 2; ++mi2) {
                const int mi = half * 2 + mi2;
                #pragma unroll
                for (int ni = 0; ni < 4; ++ni) {
                    const float bcol = bias[n0 + wn * 64 + ni * 16 + c15];
                    #pragma unroll
                    for (int p = 0; p < 4; ++p)
                        epf[(mi2 * 16 + q4 * 4 + p) * 64 + ni * 16 + c15] =
                            acc[mi][ni][p] + bcol;
                }
            }
            __syncthreads();
            const int cc = l & 15, rs = l >> 4;
            #pragma unroll
            for (int i = 0; i < 8; ++i) {
                const int rl = i * 4 + rs;
                const int row = m0 + wm * 64 + half * 32 + rl;
                if (row < M) {
                    const int col = n0 + wn * 64 + cc * 4;
                    float4 v = *(const float4*)&epf[rl * 64 + cc * 4];
                    float4 xr = *(const float4*)&xres[(size_t)row * 256 + col];
                    v.x = v.x * alpha + xr.x * beta;
                    v.y = v.y * alpha + xr.y * beta;
                    v.z = v.z * alpha + xr.z * beta;
                    v.w = v.w * alpha + xr.w * beta;
                    *(float4*)&Cf[(size_t)row * 256 + col] = v;
                }
            }
        }
    }
#undef STAGE
}

// ---------------------------------------------------------------------------
// CSR build: count -> 3-phase multiblock scan -> scatter. Segment = r*NN + dst.
// ---------------------------------------------------------------------------
__global__ void count_kernel(const int* __restrict__ dst, int* __restrict__ cnt) {
    int e = blockIdx.x * 256 + threadIdx.x;
    if (e < 2 * EE) atomicAdd(&cnt[(e / EE) * NN + dst[e]], 1);
}

__global__ __launch_bounds__(1024) void scan_local_kernel(const int* __restrict__ cnt,
                                                          int* __restrict__ rowptr,
                                                          int* __restrict__ bsum) {
    __shared__ int sh[1024];
    const int t = threadIdx.x;
    const int idx = blockIdx.x * 1024 + t;
    const int c = (idx < NSEG) ? cnt[idx] : 0;
    sh[t] = c;
    __syncthreads();
    #pragma unroll
    for (int ofs = 1; ofs < 1024; ofs <<= 1) {
        int v = (t >= ofs) ? sh[t - ofs] : 0;
        __syncthreads();
        sh[t] += v;
        __syncthreads();
    }
    if (idx < NSEG) rowptr[idx] = sh[t] - c;
    if (t == 1023) bsum[blockIdx.x] = sh[1023];
}

__global__ void scan_bsum_kernel(int* __restrict__ bsum, int* __restrict__ rowptr) {
    __shared__ int sh[128];
    const int t = threadIdx.x;
    const int v = (t < SCAN_BLOCKS) ? bsum[t] : 0;
    sh[t] = v;
    __syncthreads();
    #pragma unroll
    for (int ofs = 1; ofs < 128; ofs <<= 1) {
        int u = (t >= ofs) ? sh[t - ofs] : 0;
        __syncthreads();
        sh[t] += u;
        __syncthreads();
    }
    if (t < SCAN_BLOCKS) bsum[t] = sh[t] - v;
    if (t == 127) rowptr[NSEG] = sh[127];
}

__global__ __launch_bounds__(1024) void scan_add_kernel(int* __restrict__ rowptr,
                                                        const int* __restrict__ bsum) {
    const int idx = blockIdx.x * 1024 + threadIdx.x;
    if (idx < NSEG) rowptr[idx] += bsum[blockIdx.x];
}

__global__ void scatter_kernel(const int* __restrict__ src, const int* __restrict__ dst,
                               int* __restrict__ cursor, int* __restrict__ csr_src,
                               int* __restrict__ csr_eid) {
    int e = blockIdx.x * 256 + threadIdx.x;
    if (e >= 2 * EE) return;
    int seg = (e / EE) * NN + dst[e];
    int pos = atomicAdd(&cursor[seg], 1);
    csr_src[pos] = src[e];
    csr_eid[pos] = e;   // global edge id
}

// ---------------------------------------------------------------------------
// Pass A (both relations): expatt[e,h] = exp(dot(q[dst,h], kt_r[src,h]) *
// pri[r,h]/sqrt(dk)).  32 lanes/edge; max-pass skipped (softmax shift-inv).
// ---------------------------------------------------------------------------
__global__ void edge_att_kernel(const unsigned short* __restrict__ qkv,
                                const int* __restrict__ src, const int* __restrict__ dst,
                                const float* __restrict__ pri,
                                float* __restrict__ expatt) {
    const int half = threadIdx.x >> 5;
    const int ll = threadIdx.x & 31;
    const int h = ll >> 2, quad = ll & 3;
    const int e = blockIdx.x * 8 + half;       // 0..2E
    const int r = (e >= EE) ? 1 : 0;
    const int s = src[e], d_ = dst[e];
    const size_t off = (size_t)(h * 32 + quad * 8);

    uint4 a = *(const uint4*)&qkv[(size_t)d_ * LDQKV + off];                  // q
    uint4 b = *(const uint4*)&qkv[(size_t)s * LDQKV + 256 + r * 256 + off];   // kt_r
    float p = bf_lo(a.x) * bf_lo(b.x) + bf_hi(a.x) * bf_hi(b.x)
            + bf_lo(a.y) * bf_lo(b.y) + bf_hi(a.y) * bf_hi(b.y)
            + bf_lo(a.z) * bf_lo(b.z) + bf_hi(a.z) * bf_hi(b.z)
            + bf_lo(a.w) * bf_lo(b.w) + bf_hi(a.w) * bf_hi(b.w);
    p += __shfl_xor(p, 1);
    p += __shfl_xor(p, 2);
    if (quad == 0) {
        expatt[(size_t)e * HH + h] = __expf(p * pri[r * HH + h] * RSQRT_DK);
    }
}

// ---------------------------------------------------------------------------
// Pass B (CSR gather, both relations, no atomics): one wave per node.
// tt_bf[n] = bf16( sum_r 0.5 * (sum_j e_j*vt_r[src_j]) / (sum_j e_j) )
// ---------------------------------------------------------------------------
__global__ void node_agg_kernel(const unsigned short* __restrict__ qkv,
                                const int* __restrict__ csr_src,
                                const int* __restrict__ csr_eid,
                                const int* __restrict__ rowptr,
                                const float* __restrict__ expatt,
                                unsigned short* __restrict__ tt_bf) {
    const int wave = threadIdx.x >> 6, lane = threadIdx.x & 63;
    const int n = blockIdx.x * 4 + wave;   // grid = NN/4 exact
    const int h = lane >> 3;
    const int off = lane * 4;

    float4 tot = make_float4(0.f, 0.f, 0.f, 0.f);
    #pragma unroll
    for (int r = 0; r < 2; ++r) {
        const int seg = r * NN + n;
        const int j0 = rowptr[seg], j1 = rowptr[seg + 1];
        float4 acc = make_float4(0.f, 0.f, 0.f, 0.f);
        float den = 0.f;
        for (int j = j0; j < j1; ++j) {
            const int s = csr_src[j];
            const int e = csr_eid[j];
            const float a = expatt[(size_t)e * HH + h];
            den += a;
            uint2 b = *(const uint2*)&qkv[(size_t)s * LDQKV + 768 + r * 256 + off];
            acc.x += a * bf_lo(b.x);
            acc.y += a * bf_hi(b.x);
            acc.z += a * bf_lo(b.y);
            acc.w += a * bf_hi(b.y);
        }
        const float wgt = (den > 0.f) ? 0.5f / den : 0.f;
        tot.x += acc.x * wgt; tot.y += acc.y * wgt;
        tot.z += acc.z * wgt; tot.w += acc.w * wgt;
    }
    ushort4 ob;
    ob.x = f2bf(tot.x); ob.y = f2bf(tot.y); ob.z = f2bf(tot.z); ob.w = f2bf(tot.w);
    *(ushort4*)&tt_bf[(size_t)n * 256 + off] = ob;
}

// ---------------------------------------------------------------------------
extern "C" void kernel_launch(void* const* d_in, const int* in_sizes, int n_in,
                              void* d_out, int out_size, void* d_ws, size_t ws_size,
                              hipStream_t stream) {
    const float* x       = (const float*)d_in[0];
    const int*   src     = (const int*)d_in[1];
    const int*   dst     = (const int*)d_in[2];
    const float* Wk      = (const float*)d_in[3];
    const float* bk      = (const float*)d_in[4];
    const float* Wq      = (const float*)d_in[5];
    const float* bq      = (const float*)d_in[6];
    const float* Wv      = (const float*)d_in[7];
    const float* bv      = (const float*)d_in[8];
    const float* Wa      = (const float*)d_in[9];
    const float* ba      = (const float*)d_in[10];
    const float* rel_pri = (const float*)d_in[11];
    const float* rel_att = (const float*)d_in[12];
    const float* rel_msg = (const float*)d_in[13];
    const float* skip    = (const float*)d_in[14];
    float* out = (float*)d_out;
    char* ws = (char*)d_ws;

    const size_t ND = (size_t)NN * DD;
    size_t off = 0;
    unsigned short* x_bf   = (unsigned short*)(ws + off); off += (size_t)MPAD * DD * 2;     // 25.6MB
    unsigned short* qkv_bf = (unsigned short*)(ws + off); off += (size_t)NN * LDQKV * 2;    // 128MB
    unsigned short* tt_bf  = (unsigned short*)(ws + off); off += (size_t)MPAD * DD * 2;     // 25.6MB
    float*          expatt = (float*)(ws + off);          off += (size_t)2 * EE * HH * 4;   // 12.8MB
    unsigned short* wqkv_t = (unsigned short*)(ws + off); off += (size_t)LDQKV * 256 * 2;
    unsigned short* wa_t   = (unsigned short*)(ws + off); off += (size_t)256 * 256 * 2;
    float*          bb     = (float*)(ws + off);          off += LDQKV * 4;
    int*            cnt    = (int*)(ws + off);            off += (size_t)NSEG * 4;
    int*            rowptr = (int*)(ws + off);            off += (size_t)(NSEG + 1) * 4;
    int*            cursor = (int*)(ws + off);            off += (size_t)NSEG * 4;
    int*            bsum   = (int*)(ws + off);            off += 128 * 4;
    int*            csr_src= (int*)(ws + off);            off += (size_t)2 * EE * 4;
    int*            csr_eid= (int*)(ws + off);            off += (size_t)2 * EE * 4;
    if (ws_size < off) return;

    // --- casts / folds ---
    cast_x_kernel<<<(int)(ND / 1024), 256, 0, stream>>>(x, x_bf);
    fold_qkv_kernel<<<LDQKV, 256, 0, stream>>>(Wq, Wk, Wv, bq, bk, bv,
                                               rel_att, rel_msg, wqkv_t, bb);
    cast_wa_kernel<<<256, 256, 0, stream>>>(Wa, wa_t);

    // --- fused wide projection: qkv[50000,1280] bf16 (q | kt0 | kt1 | vt0 | vt1) ---
    dim3 g_qkv(LDQKV / 128, MPAD / 128);   // N-tiles fastest -> A-panel reuse
    mfma_gemm<<<g_qkv, 256, 0, stream>>>(x_bf, wqkv_t, bb, qkv_bf, nullptr,
                                         NN, LDQKV, nullptr, nullptr);

    // --- CSR build ---
    hipMemsetAsync(cnt, 0, (size_t)NSEG * 4, stream);
    const int eg = (2 * EE + 255) / 256;
    count_kernel<<<eg, 256, 0, stream>>>(dst, cnt);
    scan_local_kernel<<<SCAN_BLOCKS, 1024, 0, stream>>>(cnt, rowptr, bsum);
    scan_bsum_kernel<<<1, 128, 0, stream>>>(bsum, rowptr);
    scan_add_kernel<<<SCAN_BLOCKS, 1024, 0, stream>>>(rowptr, bsum);
    hipMemcpyAsync(cursor, rowptr, (size_t)NSEG * 4, hipMemcpyDeviceToDevice, stream);
    scatter_kernel<<<eg, 256, 0, stream>>>(src, dst, cursor, csr_src, csr_eid);

    // --- attention (both relations) + gather-aggregate ---
    edge_att_kernel<<<2 * EE / 8, 256, 0, stream>>>(qkv_bf, src, dst, rel_pri, expatt);
    node_agg_kernel<<<NN / 4, 256, 0, stream>>>(qkv_bf, csr_src, csr_eid, rowptr,
                                                expatt, tt_bf);

    // --- output projection with skip gate (fp32 out) ---
    dim3 g_out(DD / 128, MPAD / 128);
    mfma_gemm<<<g_out, 256, 0, stream>>>(tt_bf, wa_t, ba, nullptr, out,
                                         NN, DD, x, skip);
}